// Round 14
// baseline (506.009 us; speedup 1.0000x reference)
//
#include <hip/hip_runtime.h>
#include <math.h>

#define N_NODES 100000
#define N_EV    50000
#define NF4     25000   // N_NODES/4
#define CAP     6144    // candidate list capacity per community (2-level ladder bound)
#define MAXE    24      // max events per node (Poisson(1) over 100K nodes: max ~9)

typedef __attribute__((ext_vector_type(8))) short short8;
typedef __attribute__((ext_vector_type(4))) float f32x4;

static __device__ __forceinline__ short f2bf(float f) {
    union { float f; unsigned u; } v; v.f = f;
    unsigned r = (v.u + 0x7FFFu + ((v.u >> 16) & 1u)) >> 16;
    return (short)r;
}
static __device__ __forceinline__ float bf2f(short h) {
    union { unsigned u; float f; } v; v.u = ((unsigned)(unsigned short)h) << 16;
    return v.f;
}
// cos via v_cos_f32 (input in revolutions, fract-reduced). ~1 ulp on [0,1).
static __device__ __forceinline__ float fast_cos(float x) {
    float r = x * 0.15915494309189535f;
    r = r - floorf(r);
    return __builtin_amdgcn_cosf(r);
}
// sigmoid / tanh via v_exp_f32 (2^x) + v_rcp_f32
static __device__ __forceinline__ float fast_sigmoid(float x) {
    float e = __builtin_amdgcn_exp2f(-1.4426950408889634f * x);   // exp(-x)
    return __builtin_amdgcn_rcpf(1.f + e);
}
static __device__ __forceinline__ float fast_tanh(float x) {
    float e = __builtin_amdgcn_exp2f(2.8853900817779268f * x);    // exp(2x)
    return 1.f - 2.f * __builtin_amdgcn_rcpf(e + 1.f);
}

// ---------------- build GRU weight matrix in MFMA-fragment order (bf16) ----------------
__global__ void k_build(const float* __restrict__ W_ih, const float* __restrict__ b_ih,
                        const float* __restrict__ W_hh, const float* __restrict__ b_hh,
                        short* __restrict__ Wbf, float* __restrict__ bcat) {
    int idx = blockIdx.x * 256 + threadIdx.x;   // 512*512 = 262144
    int j = idx & 7, lane = (idx >> 3) & 63, sub = idx >> 9;
    int ks = sub & 15, NB = sub >> 4;
    int k = ks * 32 + ((lane >> 4) & 3) * 8 + j;
    int o = NB * 16 + (lane & 15);
    int g = o >> 7, d = o & 127;
    float v;
    if (g == 0)      v = W_ih[d * 512 + k] + (k < 128 ? W_hh[d * 128 + k] : 0.f);
    else if (g == 1) v = W_ih[(128 + d) * 512 + k] + (k < 128 ? W_hh[(128 + d) * 128 + k] : 0.f);
    else if (g == 2) v = W_ih[(256 + d) * 512 + k];
    else             v = (k < 128 ? W_hh[(256 + d) * 128 + k] : 0.f);
    Wbf[idx] = f2bf(v);
    if (idx < 512) {
        int gg = idx >> 7, dd = idx & 127;
        float b;
        if (gg == 0)      b = b_ih[dd] + b_hh[dd];
        else if (gg == 1) b = b_ih[128 + dd] + b_hh[128 + dd];
        else if (gg == 2) b = b_ih[256 + dd];
        else              b = b_hh[256 + dd];
        bcat[idx] = b;
    }
}

// ---------------- normalize centroids + pack hi/lo A-fragments ----------------
__global__ void k_cen(const float* __restrict__ centroids,
                      short* __restrict__ cenf_hi, short* __restrict__ cenf_lo) {
    int c = blockIdx.x, t = threadIdx.x;  // 128 threads
    float v = centroids[c * 128 + t];
    float ss = v * v;
    #pragma unroll
    for (int m = 1; m < 64; m <<= 1) ss += __shfl_xor(ss, m);
    __shared__ float tmp[2];
    if ((t & 63) == 0) tmp[t >> 6] = ss;
    __syncthreads();
    float tot = tmp[0] + tmp[1];
    float nv = v / (sqrtf(tot) + 1e-8f);
    short hi = f2bf(nv);
    short lo = f2bf(nv - bf2f(hi));
    int ct = c >> 4, c_l = c & 15, kstep = t >> 5, kj = t & 31;
    int lane = c_l + 16 * (kj >> 3), j = kj & 7;
    int fidx = ((ct * 4 + kstep) * 64 + lane) * 8 + j;
    cenf_hi[fidx] = hi;
    cenf_lo[fidx] = lo;
}

// ---------------- pack proj_W hi/lo B-fragments ----------------
__global__ void k_packW(const float* __restrict__ proj_W,
                        short* __restrict__ pw_hi, short* __restrict__ pw_lo) {
    int idx = blockIdx.x * 256 + threadIdx.x;   // 16384
    int k = idx >> 7, p = idx & 127;
    float v = proj_W[k * 128 + p];
    short hi = f2bf(v);
    short lo = f2bf(v - bf2f(hi));
    int pt = p >> 4, p_l = p & 15, kstep = k >> 5, kj = k & 31;
    int lane = p_l + 16 * (kj >> 3), j = kj & 7;
    int fidx = ((pt * 4 + kstep) * 64 + lane) * 8 + j;
    pw_hi[fidx] = hi;
    pw_lo[fidx] = lo;
}

// ---------------- event slot-list fill ----------------
__global__ __launch_bounds__(256) void k_fill(
        const float* __restrict__ t_arr, const int* __restrict__ src,
        const int* __restrict__ dst, int* __restrict__ cnt_i,
        int4* __restrict__ elist) {
    int e = blockIdx.x * 256 + threadIdx.x;   // [0, 2E)
    if (e >= 2 * N_EV) return;
    int eb  = e < N_EV ? e : e - N_EV;
    int idx = e < N_EV ? src[eb] : dst[eb];
    int oth = e < N_EV ? dst[eb] : src[eb];
    float tt = t_arr[eb];
    int p = atomicAdd(&cnt_i[idx], 1);
    if (p < MAXE)
        elist[(size_t)idx * MAXE + p] = make_int4(eb, oth, __float_as_int(tt), 0);
}

// ---------------- fused gather+GRU via MFMA bf16 (32 nodes/block, 512 threads) ----------------
__global__ __launch_bounds__(512, 4) void k_gru(
        const float* __restrict__ node_memory, const float* __restrict__ last_update,
        const float* __restrict__ event_feat,
        const float* __restrict__ time_w, const float* __restrict__ time_b,
        const int* __restrict__ cnt_i, const int4* __restrict__ elist,
        const short* __restrict__ Wbf, const float* __restrict__ bcat,
        float* __restrict__ new_mem) {
    __shared__ __align__(16) short Ab[32 * 512];   // 32 KiB
    int t = threadIdx.x;
    int n0 = blockIdx.x * 32;
    int g = t >> 4, q = t & 15;       // node group 0..31, lane-in-group 0..15
    int n = n0 + g;
    int rawc = cnt_i[n];
    int ec = rawc < MAXE ? rawc : MAXE;
    float lu = last_update[n];
    float tw[8], tb[8];
    #pragma unroll
    for (int j = 0; j < 8; j++) { tw[j] = time_w[q * 8 + j]; tb[j] = time_b[q * 8 + j]; }
    float ao[8], af[8], at[8];
    #pragma unroll
    for (int j = 0; j < 8; j++) { ao[j] = 0.f; af[j] = 0.f; at[j] = 0.f; }
    const int4* ep = elist + (size_t)n * MAXE;
    // --- first 4 events: unrolled, masked, independent loads (latency overlap) ---
    #pragma unroll
    for (int e = 0; e < 4; e++) {
        if (e < ec) {
            int4 ev = ep[e];
            int eb = ev.x, oth = ev.y;
            float dt = __int_as_float(ev.z) - lu;
            const float4* om = (const float4*)&node_memory[(size_t)oth * 128 + q * 8];
            const float4* ef = (const float4*)&event_feat[(size_t)eb * 128 + q * 8];
            float4 o0 = om[0], o1 = om[1];
            float4 f0 = ef[0], f1 = ef[1];
            ao[0] += o0.x; ao[1] += o0.y; ao[2] += o0.z; ao[3] += o0.w;
            ao[4] += o1.x; ao[5] += o1.y; ao[6] += o1.z; ao[7] += o1.w;
            af[0] += f0.x; af[1] += f0.y; af[2] += f0.z; af[3] += f0.w;
            af[4] += f1.x; af[5] += f1.y; af[6] += f1.z; af[7] += f1.w;
            #pragma unroll
            for (int j = 0; j < 8; j++) at[j] += fast_cos(fmaf(dt, tw[j], tb[j]));
        }
    }
    // --- rare tail (>4 events): serial ---
    for (int e = 4; e < ec; e++) {
        int4 ev = ep[e];
        int eb = ev.x, oth = ev.y;
        float dt = __int_as_float(ev.z) - lu;
        const float4* om = (const float4*)&node_memory[(size_t)oth * 128 + q * 8];
        const float4* ef = (const float4*)&event_feat[(size_t)eb * 128 + q * 8];
        float4 o0 = om[0], o1 = om[1];
        float4 f0 = ef[0], f1 = ef[1];
        ao[0] += o0.x; ao[1] += o0.y; ao[2] += o0.z; ao[3] += o0.w;
        ao[4] += o1.x; ao[5] += o1.y; ao[6] += o1.z; ao[7] += o1.w;
        af[0] += f0.x; af[1] += f0.y; af[2] += f0.z; af[3] += f0.w;
        af[4] += f1.x; af[5] += f1.y; af[6] += f1.z; af[7] += f1.w;
        #pragma unroll
        for (int j = 0; j < 8; j++) at[j] += fast_cos(fmaf(dt, tw[j], tb[j]));
    }
    float inv = 1.f / fmaxf((float)rawc, 1.f);
    #pragma unroll
    for (int pass = 0; pass < 4; pass++) {
        float vals[8];
        if (pass == 0) {
            const float4* p = (const float4*)&node_memory[(size_t)n * 128 + q * 8];
            float4 x = p[0], y = p[1];
            vals[0]=x.x; vals[1]=x.y; vals[2]=x.z; vals[3]=x.w;
            vals[4]=y.x; vals[5]=y.y; vals[6]=y.z; vals[7]=y.w;
        } else if (pass == 1) {
            #pragma unroll
            for (int j = 0; j < 8; j++) vals[j] = ao[j] * inv;
        } else if (pass == 2) {
            #pragma unroll
            for (int j = 0; j < 8; j++) vals[j] = af[j] * inv;
        } else {
            #pragma unroll
            for (int j = 0; j < 8; j++) vals[j] = at[j] * inv;
        }
        int k0 = q * 8 + pass * 128;
        int mb = g >> 4, ks = k0 >> 5;
        int lane = ((k0 >> 3) & 3) * 16 + (g & 15);
        int gi = (mb * 16 + ks) * 64 + lane;
        gi ^= ((gi >> 4) & 7);
        short8 sv;
        #pragma unroll
        for (int j = 0; j < 8; j++) sv[j] = f2bf(vals[j]);
        *(short8*)&Ab[gi * 8] = sv;
    }
    __syncthreads();

    int w = t >> 6, l = t & 63;
    f32x4 acc[2][4];   // [row-tile][gate]
    #pragma unroll
    for (int mb = 0; mb < 2; mb++)
        #pragma unroll
        for (int gg = 0; gg < 4; gg++) acc[mb][gg] = (f32x4){0.f, 0.f, 0.f, 0.f};

    const short8* Bp = (const short8*)Wbf;
    #pragma unroll 4
    for (int ks = 0; ks < 16; ks++) {
        short8 afr[2];
        #pragma unroll
        for (int mb = 0; mb < 2; mb++) {
            int gi = (mb * 16 + ks) * 64 + l;
            gi ^= ((gi >> 4) & 7);
            afr[mb] = *(const short8*)&Ab[gi * 8];
        }
        #pragma unroll
        for (int gate = 0; gate < 4; gate++) {
            short8 bfr = Bp[(((w + 8 * gate) * 16 + ks) * 64) + l];
            acc[0][gate] = __builtin_amdgcn_mfma_f32_16x16x32_bf16(afr[0], bfr, acc[0][gate], 0, 0, 0);
            acc[1][gate] = __builtin_amdgcn_mfma_f32_16x16x32_bf16(afr[1], bfr, acc[1][gate], 0, 0, 0);
        }
    }

    int c_l = l & 15, rq = l >> 4;
    int d = w * 16 + c_l;
    float br = bcat[d], bz = bcat[128 + d], bn = bcat[256 + d], bh = bcat[384 + d];
    #pragma unroll
    for (int mb = 0; mb < 2; mb++)
        #pragma unroll
        for (int r = 0; r < 4; r++) {
            int nn = n0 + mb * 16 + rq * 4 + r;
            int cn = cnt_i[nn];
            float h = node_memory[(size_t)nn * 128 + d];
            float rs = acc[mb][0][r] + br;
            float zs = acc[mb][1][r] + bz;
            float gn = acc[mb][2][r] + bn;
            float gh = acc[mb][3][r] + bh;
            float r_ = fast_sigmoid(rs);
            float z_ = fast_sigmoid(zs);
            float nn2 = fast_tanh(gn + r_ * gh);
            float nm = (1.f - z_) * nn2 + z_ * h;
            new_mem[(size_t)nn * 128 + d] = (cn > 0) ? nm : h;
        }
}

// ---------------- k_sim: feat -> proj -> normalize -> sim via split-bf16 MFMA ----------------
__global__ __launch_bounds__(256, 2) void k_sim(
        const float* __restrict__ new_mem, const float* __restrict__ node_features,
        const short* __restrict__ pw_hi, const short* __restrict__ pw_lo,
        const float* __restrict__ proj_b,
        const short* __restrict__ cenf_hi, const short* __restrict__ cenf_lo,
        float* __restrict__ simT) {
    __shared__ __align__(16) float feat[64 * 128];   // 32 KB, XOR-swizzled 16B granules
    __shared__ __align__(16) short pfh[64 * 128];    // 16 KB
    __shared__ __align__(16) short pfl[64 * 128];    // 16 KB
    int t = threadIdx.x;
    int n0 = blockIdx.x * 64;

    #pragma unroll
    for (int r = 0; r < 8; r++) {
        int idx = r * 256 + t;            // granule 0..2047
        int node = idx >> 5, gk = idx & 31;
        float4 v = make_float4(0.f, 0.f, 0.f, 0.f);
        int n = n0 + node;
        if (n < N_NODES) {
            float4 a = *(const float4*)&new_mem[(size_t)n * 128 + gk * 4];
            float4 b = *(const float4*)&node_features[(size_t)n * 128 + gk * 4];
            v = make_float4(a.x + b.x, a.y + b.y, a.z + b.z, a.w + b.w);
        }
        int gs = gk ^ (node & 7);
        *(float4*)&feat[(node * 32 + gs) * 4] = v;
    }
    __syncthreads();

    int w = t >> 6, l = t & 63;
    int lm = l & 15, lk = l >> 4;

    f32x4 pacc[8];
    #pragma unroll
    for (int nb = 0; nb < 8; nb++) pacc[nb] = (f32x4){0.f, 0.f, 0.f, 0.f};
    #pragma unroll
    for (int ks = 0; ks < 4; ks++) {
        int node = w * 16 + lm;
        int gk0 = ks * 8 + lk * 2;
        float4 a0 = *(const float4*)&feat[(node * 32 + (gk0 ^ (node & 7))) * 4];
        float4 a1 = *(const float4*)&feat[(node * 32 + ((gk0 + 1) ^ (node & 7))) * 4];
        float av[8] = {a0.x, a0.y, a0.z, a0.w, a1.x, a1.y, a1.z, a1.w};
        short8 Ah, Al;
        #pragma unroll
        for (int j = 0; j < 8; j++) {
            short h = f2bf(av[j]);
            Ah[j] = h;
            Al[j] = f2bf(av[j] - bf2f(h));
        }
        #pragma unroll
        for (int nb = 0; nb < 8; nb++) {
            int fidx = ((nb * 4 + ks) * 64 + l) * 8;
            short8 Bh = *(const short8*)&pw_hi[fidx];
            short8 Bl = *(const short8*)&pw_lo[fidx];
            pacc[nb] = __builtin_amdgcn_mfma_f32_16x16x32_bf16(Ah, Bh, pacc[nb], 0, 0, 0);
            pacc[nb] = __builtin_amdgcn_mfma_f32_16x16x32_bf16(Ah, Bl, pacc[nb], 0, 0, 0);
            pacc[nb] = __builtin_amdgcn_mfma_f32_16x16x32_bf16(Al, Bh, pacc[nb], 0, 0, 0);
        }
    }
    float ssq[4] = {0.f, 0.f, 0.f, 0.f};
    #pragma unroll
    for (int nb = 0; nb < 8; nb++) {
        float pb = proj_b[nb * 16 + lm];
        #pragma unroll
        for (int r = 0; r < 4; r++) {
            pacc[nb][r] += pb;
            ssq[r] = fmaf(pacc[nb][r], pacc[nb][r], ssq[r]);
        }
    }
    #pragma unroll
    for (int m = 1; m < 16; m <<= 1)
        #pragma unroll
        for (int r = 0; r < 4; r++) ssq[r] += __shfl_xor(ssq[r], m);
    float inv[4];
    #pragma unroll
    for (int r = 0; r < 4; r++) inv[r] = 1.f / (sqrtf(ssq[r]) + 1e-8f);
    #pragma unroll
    for (int nb = 0; nb < 8; nb++)
        #pragma unroll
        for (int r = 0; r < 4; r++) {
            float v = pacc[nb][r] * inv[r];
            short h = f2bf(v);
            short lo2 = f2bf(v - bf2f(h));
            int node = w * 16 + lk * 4 + r;
            int p = nb * 16 + lm;
            int g = node * 16 + (((p >> 3)) ^ (node & 7));
            int si = g * 8 + (p & 7);
            pfh[si] = h;
            pfl[si] = lo2;
        }
    __syncthreads();

    f32x4 sacc[4][4];
    #pragma unroll
    for (int ct = 0; ct < 4; ct++)
        #pragma unroll
        for (int mt = 0; mt < 4; mt++) sacc[ct][mt] = (f32x4){0.f, 0.f, 0.f, 0.f};
    #pragma unroll
    for (int ks = 0; ks < 4; ks++) {
        short8 Bh[4], Bl[4];
        #pragma unroll
        for (int mt = 0; mt < 4; mt++) {
            int node = mt * 16 + lm;
            int g = node * 16 + ((ks * 4 + lk) ^ (node & 7));
            Bh[mt] = *(const short8*)&pfh[g * 8];
            Bl[mt] = *(const short8*)&pfl[g * 8];
        }
        #pragma unroll
        for (int ct = 0; ct < 4; ct++) {
            int ctg = w * 4 + ct;
            int fidx = ((ctg * 4 + ks) * 64 + l) * 8;
            short8 Ah = *(const short8*)&cenf_hi[fidx];
            short8 Al = *(const short8*)&cenf_lo[fidx];
            #pragma unroll
            for (int mt = 0; mt < 4; mt++) {
                sacc[ct][mt] = __builtin_amdgcn_mfma_f32_16x16x32_bf16(Ah, Bh[mt], sacc[ct][mt], 0, 0, 0);
                sacc[ct][mt] = __builtin_amdgcn_mfma_f32_16x16x32_bf16(Ah, Bl[mt], sacc[ct][mt], 0, 0, 0);
                sacc[ct][mt] = __builtin_amdgcn_mfma_f32_16x16x32_bf16(Al, Bh[mt], sacc[ct][mt], 0, 0, 0);
            }
        }
    }
    #pragma unroll
    for (int ct = 0; ct < 4; ct++) {
        int cbase = (w * 4 + ct) * 16 + lk * 4;
        #pragma unroll
        for (int r = 0; r < 4; r++) {
            size_t rowoff = (size_t)(cbase + r) * N_NODES;
            #pragma unroll
            for (int mt = 0; mt < 4; mt++) {
                int n = n0 + mt * 16 + lm;
                if (n < N_NODES) simT[rowoff + n] = sacc[ct][mt][r];
            }
        }
    }
}

// ---------------- binned Michelot fixpoint (device; bin-edge lower-bound sums) ----------------
static __device__ float tau_eval(const float* __restrict__ g, int cid, float lo, float w) {
    float K[32], S[32];
    #pragma unroll
    for (int j = 0; j < 32; j++)
        K[j] = g[cid * 128 + j] + g[cid * 128 + 32 + j] + g[cid * 128 + 64 + j] + g[cid * 128 + 96 + j];
    float acc = 0.f;
    for (int b = 31; b >= 0; b--) {
        float Kn = (b == 31) ? 0.f : K[b + 1];
        acc += (K[b] - Kn) * (lo + b * w);
        S[b] = acc;
    }
    float tau = (S[0] - 1.f) / fmaxf(K[0], 1.f);
    float best = tau;
    int jprev = -1;
    for (int it = 0; it < 48; it++) {
        int j = (int)floorf((tau - lo) / w);
        j = j < 0 ? 0 : (j > 31 ? 31 : j);
        if (j > 0 && lo + j * w > tau) j--;   // cut must be <= tau
        float Kj = K[j];
        if (Kj < 0.5f) break;
        float tn = (S[j] - 1.f) / Kj;
        if (tn > best) best = tn;
        if (j == jprev) break;
        jprev = j;
        tau = tn;
    }
    return best;
}

// ---------------- ladder pass: wave-ballot counts over 32 thresholds (atomic-free) ----------------
template <int LVL>
__global__ __launch_bounds__(256) void k_lad(const float* __restrict__ simT,
                                             const float* __restrict__ g0,
                                             float* __restrict__ gout) {
    constexpr float W = (LVL == 0) ? 0.0625f : 0.008f;
    int cid = blockIdx.x >> 2, slice = blockIdx.x & 3;
    int t = threadIdx.x, l = t & 63, wv = t >> 6;
    __shared__ float lo_s;
    if (t == 0) {
        float lo = -1.03125f;
        if (LVL == 1) lo = tau_eval(g0, cid, -1.03125f, 0.0625f);
        lo_s = lo;
    }
    __syncthreads();
    float lo = lo_s;
    const float4* z4 = (const float4*)(simT + (size_t)cid * N_NODES);
    int cnt[32];
    #pragma unroll
    for (int j = 0; j < 32; j++) cnt[j] = 0;
    int base0 = slice * 6250, end = base0 + 6250;
    for (int base = base0; base < end; base += 256) {
        int i = base + t;
        float4 a = make_float4(-2.f, -2.f, -2.f, -2.f);   // below every threshold
        if (i < end) a = z4[i];
        float b0 = a.x - lo, b1 = a.y - lo, b2 = a.z - lo, b3 = a.w - lo;
        #pragma unroll
        for (int j = 0; j < 32; j++) {
            float T = j * W;
            cnt[j] += __popcll(__ballot(b0 > T)) + __popcll(__ballot(b1 > T))
                    + __popcll(__ballot(b2 > T)) + __popcll(__ballot(b3 > T));
        }
    }
    __shared__ int red[4][32];
    if (l == 0) {
        #pragma unroll
        for (int j = 0; j < 32; j++) red[wv][j] = cnt[j];
    }
    __syncthreads();
    if (t < 32) {
        float v = (float)(red[0][t] + red[1][t] + red[2][t] + red[3][t]);
        gout[cid * 128 + slice * 32 + t] = v;
    }
}

// ---------------- gather candidates z > thresh (level-1 threshold, big CAP) ----------------
__global__ __launch_bounds__(256) void k_gather(const float* __restrict__ simT,
                                                const float* __restrict__ g0,
                                                const float* __restrict__ g1,
                                                int* __restrict__ ccount,
                                                float2* __restrict__ clist) {
    int cid = blockIdx.x >> 2, slice = blockIdx.x & 3;
    __shared__ float th_s;
    if (threadIdx.x == 0) {
        float t1 = tau_eval(g0, cid, -1.03125f, 0.0625f);
        th_s = tau_eval(g1, cid, t1, 0.008f) - 1e-5f;
    }
    __syncthreads();
    float th = th_s;
    const float4* z4 = (const float4*)(simT + (size_t)cid * N_NODES);
    int t = threadIdx.x;
    int end = slice * 6250 + 6250;
    for (int i = slice * 6250 + t; i < end; i += 256) {
        float4 a = z4[i];
        int nb = i * 4;
        #define GATH(v, j) if ((v) > th) { int p = atomicAdd(&ccount[cid], 1); \
            if (p < CAP) clist[(size_t)cid * CAP + p] = make_float2((v), __int_as_float(nb + (j))); }
        GATH(a.x, 0) GATH(a.y, 1) GATH(a.z, 2) GATH(a.w, 3)
        #undef GATH
    }
}

// ---------------- exact Michelot on candidates + c_mem accumulation ----------------
__global__ __launch_bounds__(256) void k_csolve(
        const float* __restrict__ simT, const float* __restrict__ new_mem,
        const int* __restrict__ ccount, const float2* __restrict__ clist,
        float* __restrict__ c_mem) {
    int c = blockIdx.x, t = threadIdx.x;  // 256 threads
    __shared__ float zv[CAP];
    __shared__ int   zn[CAP];
    __shared__ float redS[4], redK[4], part[256];
    int raw = ccount[c];
    if (raw == 0) {
        if (t < 128) c_mem[c * 128 + t] = 0.f;
        return;
    }
    float tau;
    if (raw <= CAP) {
        int cnt = raw;
        for (int i = t; i < cnt; i += 256) {
            float2 e = clist[(size_t)c * CAP + i];
            zv[i] = e.x; zn[i] = __float_as_int(e.y);
        }
        __syncthreads();
        float ls = 0.f;
        for (int i = t; i < cnt; i += 256) ls += zv[i];
        #pragma unroll
        for (int m = 1; m < 64; m <<= 1) ls += __shfl_xor(ls, m);
        if ((t & 63) == 0) redS[t >> 6] = ls;
        __syncthreads();
        tau = (redS[0] + redS[1] + redS[2] + redS[3] - 1.f) / (float)cnt;
        float kprev = (float)cnt;
        for (int it = 0; it < 64; it++) {
            float s = 0.f, k = 0.f;
            for (int i = t; i < cnt; i += 256) {
                float v = zv[i];
                if (v > tau) { s += v; k += 1.f; }
            }
            #pragma unroll
            for (int m = 1; m < 64; m <<= 1) { s += __shfl_xor(s, m); k += __shfl_xor(k, m); }
            __syncthreads();
            if ((t & 63) == 0) { redS[t >> 6] = s; redK[t >> 6] = k; }
            __syncthreads();
            float S_ = redS[0] + redS[1] + redS[2] + redS[3];
            float K_ = redK[0] + redK[1] + redK[2] + redK[3];
            if (K_ == kprev || K_ < 0.5f) break;
            kprev = K_;
            tau = (S_ - 1.f) / K_;
        }
        int d = t & 127, half = t >> 7;
        float acc = 0.f;
        for (int i = half; i < cnt; i += 2) {
            float w = zv[i] - tau;
            if (w > 0.f) acc = fmaf(w, new_mem[(size_t)zn[i] * 128 + d], acc);
        }
        part[t] = acc;
        __syncthreads();
        if (t < 128) c_mem[c * 128 + t] = part[t] + part[t + 128];
    } else {
        const float* z = simT + (size_t)c * N_NODES;
        float ls = 0.f;
        for (int n = t; n < N_NODES; n += 256) ls += z[n];
        #pragma unroll
        for (int m = 1; m < 64; m <<= 1) ls += __shfl_xor(ls, m);
        if ((t & 63) == 0) redS[t >> 6] = ls;
        __syncthreads();
        tau = (redS[0] + redS[1] + redS[2] + redS[3] - 1.f) / (float)N_NODES;
        float kprev = -1.f;
        for (int it = 0; it < 64; it++) {
            float s = 0.f, k = 0.f;
            for (int n = t; n < N_NODES; n += 256) {
                float v = z[n];
                if (v > tau) { s += v; k += 1.f; }
            }
            #pragma unroll
            for (int m = 1; m < 64; m <<= 1) { s += __shfl_xor(s, m); k += __shfl_xor(k, m); }
            __syncthreads();
            if ((t & 63) == 0) { redS[t >> 6] = s; redK[t >> 6] = k; }
            __syncthreads();
            float S_ = redS[0] + redS[1] + redS[2] + redS[3];
            float K_ = redK[0] + redK[1] + redK[2] + redK[3];
            if (K_ == kprev || K_ < 0.5f) break;
            kprev = K_;
            tau = (S_ - 1.f) / K_;
        }
        int d = t & 127, half = t >> 7;
        float acc = 0.f;
        for (int n = half; n < N_NODES; n += 2) {
            float w = z[n] - tau;
            if (w > 0.f) acc = fmaf(w, new_mem[(size_t)n * 128 + d], acc);
        }
        part[t] = acc;
        __syncthreads();
        if (t < 128) c_mem[c * 128 + t] = part[t] + part[t + 128];
    }
}

// ---------------- node sparsemax (register Michelot) + ballot-compacted mix -> emb ----------------
__global__ __launch_bounds__(512) void k_emb(
        const float* __restrict__ simT, const float* __restrict__ c_mem,
        float* __restrict__ out) {
    __shared__ float zb[32 * 257];
    __shared__ float2 suppl[32][64];
    __shared__ int suppc[32];
    int t = threadIdx.x;
    int n0 = blockIdx.x * 32;
    #pragma unroll
    for (int r = 0; r < 16; r++) {
        int n_l = t & 31, c = r * 16 + (t >> 5);
        zb[n_l * 257 + c] = simT[(size_t)c * N_NODES + (n0 + n_l)];
    }
    __syncthreads();
    int n_l = t >> 4, g = t & 15;
    const float* zr = zb + n_l * 257;
    float zv[16];
    #pragma unroll
    for (int j = 0; j < 16; j++) zv[j] = zr[g + 16 * j];
    float s = 0.f;
    #pragma unroll
    for (int j = 0; j < 16; j++) s += zv[j];
    #pragma unroll
    for (int m = 1; m < 16; m <<= 1) s += __shfl_xor(s, m);
    float tau = (s - 1.f) / 256.f;
    float kprev = -1.f;
    for (int it = 0; it < 40; it++) {
        float ls = 0.f, lk = 0.f;
        #pragma unroll
        for (int j = 0; j < 16; j++) {
            float v = zv[j];
            if (v > tau) { ls += v; lk += 1.f; }
        }
        #pragma unroll
        for (int m = 1; m < 16; m <<= 1) { ls += __shfl_xor(ls, m); lk += __shfl_xor(lk, m); }
        if (lk == kprev) break;
        kprev = lk;
        tau = (ls - 1.f) / lk;
    }
    int gw = (t >> 4) & 3;   // group index within wave
    int base = 0;
    #pragma unroll
    for (int j = 0; j < 16; j++) {
        float m = zv[j] - tau;
        bool pred = m > 0.f;
        unsigned long long mask = __ballot(pred);
        unsigned gm = (unsigned)((mask >> (gw * 16)) & 0xFFFFull);
        if (pred) {
            int idx = base + __popc(gm & ((1u << g) - 1u));
            if (idx < 64) suppl[n_l][idx] = make_float2(m, __int_as_float(g + 16 * j));
        }
        base += __popc(gm);
    }
    if (g == 0) suppc[n_l] = base;
    __syncthreads();
    float acc[8];
    #pragma unroll
    for (int j = 0; j < 8; j++) acc[j] = 0.f;
    int cnt_s = suppc[n_l];
    if (cnt_s <= 64) {
        for (int i = 0; i < cnt_s; i++) {
            float2 e = suppl[n_l][i];
            int c = __float_as_int(e.y);
            const float* cm = c_mem + c * 128 + g * 8;
            #pragma unroll
            for (int j = 0; j < 8; j++) acc[j] = fmaf(e.x, cm[j], acc[j]);
        }
    } else {
        for (int c = 0; c < 256; c++) {
            float m = zr[c] - tau;
            if (m > 0.f) {
                const float* cm = c_mem + c * 128 + g * 8;
                #pragma unroll
                for (int j = 0; j < 8; j++) acc[j] = fmaf(m, cm[j], acc[j]);
            }
        }
    }
    float* op = out + (size_t)(n0 + n_l) * 128 + g * 8;
    #pragma unroll
    for (int j = 0; j < 8; j++) op[j] += acc[j];
}

extern "C" void kernel_launch(void* const* d_in, const int* in_sizes, int n_in,
                              void* d_out, int out_size, void* d_ws, size_t ws_size,
                              hipStream_t stream) {
    const float* node_memory   = (const float*)d_in[0];
    const float* last_update   = (const float*)d_in[1];
    const float* node_features = (const float*)d_in[2];
    const float* event_feat    = (const float*)d_in[3];
    const float* t_arr         = (const float*)d_in[4];
    const int*   src           = (const int*)d_in[5];
    const int*   dst           = (const int*)d_in[6];
    const float* time_w        = (const float*)d_in[7];
    const float* time_b        = (const float*)d_in[8];
    const float* W_ih          = (const float*)d_in[9];
    const float* b_ih          = (const float*)d_in[10];
    const float* W_hh          = (const float*)d_in[11];
    const float* b_hh          = (const float*)d_in[12];
    const float* proj_W        = (const float*)d_in[13];
    const float* proj_b        = (const float*)d_in[14];
    const float* centroids     = (const float*)d_in[15];

    float* ws     = (float*)d_ws;
    float* simT   = ws;                                       // 256 * N floats (102.4 MB)
    int*   cnt_i  = (int*)(ws + (size_t)256 * N_NODES);       // N ints
    int4*  elist  = (int4*)(cnt_i + N_NODES);                 // N * MAXE int4 (38.4 MB)
    short* Wbf    = (short*)(elist + (size_t)N_NODES * MAXE); // 512*512 bf16
    float* bcat   = (float*)(Wbf + 512 * 512);                // 512
    float* c_mem  = bcat + 512;                               // 256*128 = 32768
    float* gc0    = c_mem + 32768;                            // 256*128
    float* gc1    = gc0 + 32768;
    int*   ccount = (int*)(gc1 + 32768);                      // 256
    float2* clist = (float2*)(ccount + 256);                  // 256*CAP float2
    short* cenf_hi = (short*)(clist + (size_t)256 * CAP);     // 32768 shorts
    short* cenf_lo = cenf_hi + 256 * 128;
    short* pw_hi   = cenf_lo + 256 * 128;
    short* pw_lo   = pw_hi + 128 * 128;
    float* out    = (float*)d_out;

    hipMemsetAsync(cnt_i, 0, N_NODES * sizeof(int), stream);
    hipMemsetAsync(ccount, 0, 256 * sizeof(int), stream);
    k_build<<<1024, 256, 0, stream>>>(W_ih, b_ih, W_hh, b_hh, Wbf, bcat);
    k_cen<<<256, 128, 0, stream>>>(centroids, cenf_hi, cenf_lo);
    k_packW<<<64, 256, 0, stream>>>(proj_W, pw_hi, pw_lo);
    k_fill<<<(2 * N_EV + 255) / 256, 256, 0, stream>>>(t_arr, src, dst, cnt_i, elist);
    k_gru<<<N_NODES / 32, 512, 0, stream>>>(node_memory, last_update, event_feat,
                                            time_w, time_b, cnt_i, elist, Wbf, bcat, out);
    k_sim<<<(N_NODES + 63) / 64, 256, 0, stream>>>(out, node_features, pw_hi, pw_lo,
                                                   proj_b, cenf_hi, cenf_lo, simT);
    k_lad<0><<<1024, 256, 0, stream>>>(simT, nullptr, gc0);
    k_lad<1><<<1024, 256, 0, stream>>>(simT, gc0, gc1);
    k_gather<<<1024, 256, 0, stream>>>(simT, gc0, gc1, ccount, clist);
    k_csolve<<<256, 256, 0, stream>>>(simT, out, ccount, clist, c_mem);
    k_emb<<<N_NODES / 32, 512, 0, stream>>>(simT, c_mem, out);
}

// Round 16
// 483.729 us; speedup vs baseline: 1.0461x; 1.0461x over previous
//
#include <hip/hip_runtime.h>
#include <math.h>

#define N_NODES 100000
#define N_EV    50000
#define CAP     6144    // candidate list capacity per community (2-level ladder bound)
#define MAXE    24      // max events per node (Poisson(1) over 100K nodes: max ~9)

typedef __attribute__((ext_vector_type(8))) short short8;
typedef __attribute__((ext_vector_type(4))) float f32x4;
typedef __attribute__((ext_vector_type(8))) _Float16 half8;

static __device__ __forceinline__ short f2bf(float f) {
    union { float f; unsigned u; } v; v.f = f;
    unsigned r = (v.u + 0x7FFFu + ((v.u >> 16) & 1u)) >> 16;
    return (short)r;
}
static __device__ __forceinline__ float bf2f(short h) {
    union { unsigned u; float f; } v; v.u = ((unsigned)(unsigned short)h) << 16;
    return v.f;
}
static __device__ __forceinline__ float fast_cos(float x) {
    float r = x * 0.15915494309189535f;
    r = r - floorf(r);
    return __builtin_amdgcn_cosf(r);
}
static __device__ __forceinline__ float fast_sigmoid(float x) {
    float e = __builtin_amdgcn_exp2f(-1.4426950408889634f * x);   // exp(-x)
    return __builtin_amdgcn_rcpf(1.f + e);
}
static __device__ __forceinline__ float fast_tanh(float x) {
    float e = __builtin_amdgcn_exp2f(2.8853900817779268f * x);    // exp(2x)
    return 1.f - 2.f * __builtin_amdgcn_rcpf(e + 1.f);
}

// ---------------- build GRU weight matrix in MFMA-fragment order (bf16) ----------------
__global__ void k_build(const float* __restrict__ W_ih, const float* __restrict__ b_ih,
                        const float* __restrict__ W_hh, const float* __restrict__ b_hh,
                        short* __restrict__ Wbf, float* __restrict__ bcat) {
    int idx = blockIdx.x * 256 + threadIdx.x;   // 512*512 = 262144
    int j = idx & 7, lane = (idx >> 3) & 63, sub = idx >> 9;
    int ks = sub & 15, NB = sub >> 4;
    int k = ks * 32 + ((lane >> 4) & 3) * 8 + j;
    int o = NB * 16 + (lane & 15);
    int g = o >> 7, d = o & 127;
    float v;
    if (g == 0)      v = W_ih[d * 512 + k] + (k < 128 ? W_hh[d * 128 + k] : 0.f);
    else if (g == 1) v = W_ih[(128 + d) * 512 + k] + (k < 128 ? W_hh[(128 + d) * 128 + k] : 0.f);
    else if (g == 2) v = W_ih[(256 + d) * 512 + k];
    else             v = (k < 128 ? W_hh[(256 + d) * 128 + k] : 0.f);
    Wbf[idx] = f2bf(v);
    if (idx < 512) {
        int gg = idx >> 7, dd = idx & 127;
        float b;
        if (gg == 0)      b = b_ih[dd] + b_hh[dd];
        else if (gg == 1) b = b_ih[128 + dd] + b_hh[128 + dd];
        else if (gg == 2) b = b_ih[256 + dd];
        else              b = b_hh[256 + dd];
        bcat[idx] = b;
    }
}

// ---------------- normalize centroids + pack hi/lo A-fragments ----------------
__global__ void k_cen(const float* __restrict__ centroids,
                      short* __restrict__ cenf_hi, short* __restrict__ cenf_lo) {
    int c = blockIdx.x, t = threadIdx.x;  // 128 threads
    float v = centroids[c * 128 + t];
    float ss = v * v;
    #pragma unroll
    for (int m = 1; m < 64; m <<= 1) ss += __shfl_xor(ss, m);
    __shared__ float tmp[2];
    if ((t & 63) == 0) tmp[t >> 6] = ss;
    __syncthreads();
    float tot = tmp[0] + tmp[1];
    float nv = v / (sqrtf(tot) + 1e-8f);
    short hi = f2bf(nv);
    short lo = f2bf(nv - bf2f(hi));
    int ct = c >> 4, c_l = c & 15, kstep = t >> 5, kj = t & 31;
    int lane = c_l + 16 * (kj >> 3), j = kj & 7;
    int fidx = ((ct * 4 + kstep) * 64 + lane) * 8 + j;
    cenf_hi[fidx] = hi;
    cenf_lo[fidx] = lo;
}

// ---------------- pack proj_W hi/lo B-fragments ----------------
__global__ void k_packW(const float* __restrict__ proj_W,
                        short* __restrict__ pw_hi, short* __restrict__ pw_lo) {
    int idx = blockIdx.x * 256 + threadIdx.x;   // 16384
    int k = idx >> 7, p = idx & 127;
    float v = proj_W[k * 128 + p];
    short hi = f2bf(v);
    short lo = f2bf(v - bf2f(hi));
    int pt = p >> 4, p_l = p & 15, kstep = k >> 5, kj = k & 31;
    int lane = p_l + 16 * (kj >> 3), j = kj & 7;
    int fidx = ((pt * 4 + kstep) * 64 + lane) * 8 + j;
    pw_hi[fidx] = hi;
    pw_lo[fidx] = lo;
}

// ---------------- event slot-list fill ----------------
__global__ __launch_bounds__(256) void k_fill(
        const float* __restrict__ t_arr, const int* __restrict__ src,
        const int* __restrict__ dst, int* __restrict__ cnt_i,
        int4* __restrict__ elist) {
    int e = blockIdx.x * 256 + threadIdx.x;   // [0, 2E)
    if (e >= 2 * N_EV) return;
    int eb  = e < N_EV ? e : e - N_EV;
    int idx = e < N_EV ? src[eb] : dst[eb];
    int oth = e < N_EV ? dst[eb] : src[eb];
    float tt = t_arr[eb];
    int p = atomicAdd(&cnt_i[idx], 1);
    if (p < MAXE)
        elist[(size_t)idx * MAXE + p] = make_int4(eb, oth, __float_as_int(tt), 0);
}

// ---------------- fused gather+GRU via MFMA bf16 (32 nodes/block, 512 threads) ----------------
__global__ __launch_bounds__(512, 4) void k_gru(
        const float* __restrict__ node_memory, const float* __restrict__ last_update,
        const float* __restrict__ event_feat,
        const float* __restrict__ time_w, const float* __restrict__ time_b,
        const int* __restrict__ cnt_i, const int4* __restrict__ elist,
        const short* __restrict__ Wbf, const float* __restrict__ bcat,
        float* __restrict__ new_mem) {
    __shared__ __align__(16) short Ab[32 * 512];   // 32 KiB
    int t = threadIdx.x;
    int n0 = blockIdx.x * 32;
    int g = t >> 4, q = t & 15;       // node group 0..31, lane-in-group 0..15
    int n = n0 + g;
    int rawc = cnt_i[n];
    int ec = rawc < MAXE ? rawc : MAXE;
    float lu = last_update[n];
    float tw[8], tb[8];
    #pragma unroll
    for (int j = 0; j < 8; j++) { tw[j] = time_w[q * 8 + j]; tb[j] = time_b[q * 8 + j]; }
    float ao[8], af[8], at[8];
    #pragma unroll
    for (int j = 0; j < 8; j++) { ao[j] = 0.f; af[j] = 0.f; at[j] = 0.f; }
    const int4* ep = elist + (size_t)n * MAXE;
    #pragma unroll
    for (int e = 0; e < 4; e++) {
        if (e < ec) {
            int4 ev = ep[e];
            int eb = ev.x, oth = ev.y;
            float dt = __int_as_float(ev.z) - lu;
            const float4* om = (const float4*)&node_memory[(size_t)oth * 128 + q * 8];
            const float4* ef = (const float4*)&event_feat[(size_t)eb * 128 + q * 8];
            float4 o0 = om[0], o1 = om[1];
            float4 f0 = ef[0], f1 = ef[1];
            ao[0] += o0.x; ao[1] += o0.y; ao[2] += o0.z; ao[3] += o0.w;
            ao[4] += o1.x; ao[5] += o1.y; ao[6] += o1.z; ao[7] += o1.w;
            af[0] += f0.x; af[1] += f0.y; af[2] += f0.z; af[3] += f0.w;
            af[4] += f1.x; af[5] += f1.y; af[6] += f1.z; af[7] += f1.w;
            #pragma unroll
            for (int j = 0; j < 8; j++) at[j] += fast_cos(fmaf(dt, tw[j], tb[j]));
        }
    }
    for (int e = 4; e < ec; e++) {
        int4 ev = ep[e];
        int eb = ev.x, oth = ev.y;
        float dt = __int_as_float(ev.z) - lu;
        const float4* om = (const float4*)&node_memory[(size_t)oth * 128 + q * 8];
        const float4* ef = (const float4*)&event_feat[(size_t)eb * 128 + q * 8];
        float4 o0 = om[0], o1 = om[1];
        float4 f0 = ef[0], f1 = ef[1];
        ao[0] += o0.x; ao[1] += o0.y; ao[2] += o0.z; ao[3] += o0.w;
        ao[4] += o1.x; ao[5] += o1.y; ao[6] += o1.z; ao[7] += o1.w;
        af[0] += f0.x; af[1] += f0.y; af[2] += f0.z; af[3] += f0.w;
        af[4] += f1.x; af[5] += f1.y; af[6] += f1.z; af[7] += f1.w;
        #pragma unroll
        for (int j = 0; j < 8; j++) at[j] += fast_cos(fmaf(dt, tw[j], tb[j]));
    }
    float inv = 1.f / fmaxf((float)rawc, 1.f);
    #pragma unroll
    for (int pass = 0; pass < 4; pass++) {
        float vals[8];
        if (pass == 0) {
            const float4* p = (const float4*)&node_memory[(size_t)n * 128 + q * 8];
            float4 x = p[0], y = p[1];
            vals[0]=x.x; vals[1]=x.y; vals[2]=x.z; vals[3]=x.w;
            vals[4]=y.x; vals[5]=y.y; vals[6]=y.z; vals[7]=y.w;
        } else if (pass == 1) {
            #pragma unroll
            for (int j = 0; j < 8; j++) vals[j] = ao[j] * inv;
        } else if (pass == 2) {
            #pragma unroll
            for (int j = 0; j < 8; j++) vals[j] = af[j] * inv;
        } else {
            #pragma unroll
            for (int j = 0; j < 8; j++) vals[j] = at[j] * inv;
        }
        int k0 = q * 8 + pass * 128;
        int mb = g >> 4, ks = k0 >> 5;
        int lane = ((k0 >> 3) & 3) * 16 + (g & 15);
        int gi = (mb * 16 + ks) * 64 + lane;
        gi ^= ((gi >> 4) & 7);
        short8 sv;
        #pragma unroll
        for (int j = 0; j < 8; j++) sv[j] = f2bf(vals[j]);
        *(short8*)&Ab[gi * 8] = sv;
    }
    __syncthreads();

    int w = t >> 6, l = t & 63;
    f32x4 acc[2][4];   // [row-tile][gate]
    #pragma unroll
    for (int mb = 0; mb < 2; mb++)
        #pragma unroll
        for (int gg = 0; gg < 4; gg++) acc[mb][gg] = (f32x4){0.f, 0.f, 0.f, 0.f};

    const short8* Bp = (const short8*)Wbf;
    #pragma unroll 4
    for (int ks = 0; ks < 16; ks++) {
        short8 afr[2];
        #pragma unroll
        for (int mb = 0; mb < 2; mb++) {
            int gi = (mb * 16 + ks) * 64 + l;
            gi ^= ((gi >> 4) & 7);
            afr[mb] = *(const short8*)&Ab[gi * 8];
        }
        #pragma unroll
        for (int gate = 0; gate < 4; gate++) {
            short8 bfr = Bp[(((w + 8 * gate) * 16 + ks) * 64) + l];
            acc[0][gate] = __builtin_amdgcn_mfma_f32_16x16x32_bf16(afr[0], bfr, acc[0][gate], 0, 0, 0);
            acc[1][gate] = __builtin_amdgcn_mfma_f32_16x16x32_bf16(afr[1], bfr, acc[1][gate], 0, 0, 0);
        }
    }

    int c_l = l & 15, rq = l >> 4;
    int d = w * 16 + c_l;
    float br = bcat[d], bz = bcat[128 + d], bn = bcat[256 + d], bh = bcat[384 + d];
    #pragma unroll
    for (int mb = 0; mb < 2; mb++)
        #pragma unroll
        for (int r = 0; r < 4; r++) {
            int nn = n0 + mb * 16 + rq * 4 + r;
            int cn = cnt_i[nn];
            float h = node_memory[(size_t)nn * 128 + d];
            float rs = acc[mb][0][r] + br;
            float zs = acc[mb][1][r] + bz;
            float gn = acc[mb][2][r] + bn;
            float gh = acc[mb][3][r] + bh;
            float r_ = fast_sigmoid(rs);
            float z_ = fast_sigmoid(zs);
            float nn2 = fast_tanh(gn + r_ * gh);
            float nm = (1.f - z_) * nn2 + z_ * h;
            new_mem[(size_t)nn * 128 + d] = (cn > 0) ? nm : h;
        }
}

// ---------------- k_sim: feat -> proj -> normalize -> sim via split-bf16 MFMA (fp16 simT) ----------------
__global__ __launch_bounds__(256, 2) void k_sim(
        const float* __restrict__ new_mem, const float* __restrict__ node_features,
        const short* __restrict__ pw_hi, const short* __restrict__ pw_lo,
        const float* __restrict__ proj_b,
        const short* __restrict__ cenf_hi, const short* __restrict__ cenf_lo,
        _Float16* __restrict__ simT) {
    __shared__ __align__(16) float feat[64 * 128];   // 32 KB, XOR-swizzled 16B granules
    __shared__ __align__(16) short pfh[64 * 128];    // 16 KB
    __shared__ __align__(16) short pfl[64 * 128];    // 16 KB
    int t = threadIdx.x;
    int n0 = blockIdx.x * 64;

    #pragma unroll
    for (int r = 0; r < 8; r++) {
        int idx = r * 256 + t;            // granule 0..2047
        int node = idx >> 5, gk = idx & 31;
        float4 v = make_float4(0.f, 0.f, 0.f, 0.f);
        int n = n0 + node;
        if (n < N_NODES) {
            float4 a = *(const float4*)&new_mem[(size_t)n * 128 + gk * 4];
            float4 b = *(const float4*)&node_features[(size_t)n * 128 + gk * 4];
            v = make_float4(a.x + b.x, a.y + b.y, a.z + b.z, a.w + b.w);
        }
        int gs = gk ^ (node & 7);
        *(float4*)&feat[(node * 32 + gs) * 4] = v;
    }
    __syncthreads();

    int w = t >> 6, l = t & 63;
    int lm = l & 15, lk = l >> 4;

    f32x4 pacc[8];
    #pragma unroll
    for (int nb = 0; nb < 8; nb++) pacc[nb] = (f32x4){0.f, 0.f, 0.f, 0.f};
    #pragma unroll
    for (int ks = 0; ks < 4; ks++) {
        int node = w * 16 + lm;
        int gk0 = ks * 8 + lk * 2;
        float4 a0 = *(const float4*)&feat[(node * 32 + (gk0 ^ (node & 7))) * 4];
        float4 a1 = *(const float4*)&feat[(node * 32 + ((gk0 + 1) ^ (node & 7))) * 4];
        float av[8] = {a0.x, a0.y, a0.z, a0.w, a1.x, a1.y, a1.z, a1.w};
        short8 Ah, Al;
        #pragma unroll
        for (int j = 0; j < 8; j++) {
            short h = f2bf(av[j]);
            Ah[j] = h;
            Al[j] = f2bf(av[j] - bf2f(h));
        }
        #pragma unroll
        for (int nb = 0; nb < 8; nb++) {
            int fidx = ((nb * 4 + ks) * 64 + l) * 8;
            short8 Bh = *(const short8*)&pw_hi[fidx];
            short8 Bl = *(const short8*)&pw_lo[fidx];
            pacc[nb] = __builtin_amdgcn_mfma_f32_16x16x32_bf16(Ah, Bh, pacc[nb], 0, 0, 0);
            pacc[nb] = __builtin_amdgcn_mfma_f32_16x16x32_bf16(Ah, Bl, pacc[nb], 0, 0, 0);
            pacc[nb] = __builtin_amdgcn_mfma_f32_16x16x32_bf16(Al, Bh, pacc[nb], 0, 0, 0);
        }
    }
    float ssq[4] = {0.f, 0.f, 0.f, 0.f};
    #pragma unroll
    for (int nb = 0; nb < 8; nb++) {
        float pb = proj_b[nb * 16 + lm];
        #pragma unroll
        for (int r = 0; r < 4; r++) {
            pacc[nb][r] += pb;
            ssq[r] = fmaf(pacc[nb][r], pacc[nb][r], ssq[r]);
        }
    }
    #pragma unroll
    for (int m = 1; m < 16; m <<= 1)
        #pragma unroll
        for (int r = 0; r < 4; r++) ssq[r] += __shfl_xor(ssq[r], m);
    float inv[4];
    #pragma unroll
    for (int r = 0; r < 4; r++) inv[r] = 1.f / (sqrtf(ssq[r]) + 1e-8f);
    #pragma unroll
    for (int nb = 0; nb < 8; nb++)
        #pragma unroll
        for (int r = 0; r < 4; r++) {
            float v = pacc[nb][r] * inv[r];
            short h = f2bf(v);
            short lo2 = f2bf(v - bf2f(h));
            int node = w * 16 + lk * 4 + r;
            int p = nb * 16 + lm;
            int g = node * 16 + (((p >> 3)) ^ (node & 7));
            int si = g * 8 + (p & 7);
            pfh[si] = h;
            pfl[si] = lo2;
        }
    __syncthreads();

    f32x4 sacc[4][4];
    #pragma unroll
    for (int ct = 0; ct < 4; ct++)
        #pragma unroll
        for (int mt = 0; mt < 4; mt++) sacc[ct][mt] = (f32x4){0.f, 0.f, 0.f, 0.f};
    #pragma unroll
    for (int ks = 0; ks < 4; ks++) {
        short8 Bh[4], Bl[4];
        #pragma unroll
        for (int mt = 0; mt < 4; mt++) {
            int node = mt * 16 + lm;
            int g = node * 16 + ((ks * 4 + lk) ^ (node & 7));
            Bh[mt] = *(const short8*)&pfh[g * 8];
            Bl[mt] = *(const short8*)&pfl[g * 8];
        }
        #pragma unroll
        for (int ct = 0; ct < 4; ct++) {
            int ctg = w * 4 + ct;
            int fidx = ((ctg * 4 + ks) * 64 + l) * 8;
            short8 Ah = *(const short8*)&cenf_hi[fidx];
            short8 Al = *(const short8*)&cenf_lo[fidx];
            #pragma unroll
            for (int mt = 0; mt < 4; mt++) {
                sacc[ct][mt] = __builtin_amdgcn_mfma_f32_16x16x32_bf16(Ah, Bh[mt], sacc[ct][mt], 0, 0, 0);
                sacc[ct][mt] = __builtin_amdgcn_mfma_f32_16x16x32_bf16(Ah, Bl[mt], sacc[ct][mt], 0, 0, 0);
                sacc[ct][mt] = __builtin_amdgcn_mfma_f32_16x16x32_bf16(Al, Bh[mt], sacc[ct][mt], 0, 0, 0);
            }
        }
    }
    #pragma unroll
    for (int ct = 0; ct < 4; ct++) {
        int cbase = (w * 4 + ct) * 16 + lk * 4;
        #pragma unroll
        for (int r = 0; r < 4; r++) {
            size_t rowoff = (size_t)(cbase + r) * N_NODES;
            #pragma unroll
            for (int mt = 0; mt < 4; mt++) {
                int n = n0 + mt * 16 + lm;
                if (n < N_NODES) simT[rowoff + n] = (_Float16)sacc[ct][mt][r];
            }
        }
    }
}

// ---------------- binned Michelot fixpoint (device; bin-edge lower-bound sums) ----------------
static __device__ float tau_eval(const float* __restrict__ g, int cid, float lo, float w) {
    float K[32], S[32];
    #pragma unroll
    for (int j = 0; j < 32; j++)
        K[j] = g[cid * 128 + j] + g[cid * 128 + 32 + j] + g[cid * 128 + 64 + j] + g[cid * 128 + 96 + j];
    float acc = 0.f;
    for (int b = 31; b >= 0; b--) {
        float Kn = (b == 31) ? 0.f : K[b + 1];
        acc += (K[b] - Kn) * (lo + b * w);
        S[b] = acc;
    }
    float tau = (S[0] - 1.f) / fmaxf(K[0], 1.f);
    float best = tau;
    int jprev = -1;
    for (int it = 0; it < 48; it++) {
        int j = (int)floorf((tau - lo) / w);
        j = j < 0 ? 0 : (j > 31 ? 31 : j);
        if (j > 0 && lo + j * w > tau) j--;   // cut must be <= tau
        float Kj = K[j];
        if (Kj < 0.5f) break;
        float tn = (S[j] - 1.f) / Kj;
        if (tn > best) best = tn;
        if (j == jprev) break;
        jprev = j;
        tau = tn;
    }
    return best;
}

// ---------------- ladder pass: wave-ballot counts over 32 thresholds (fp16 simT) ----------------
template <int LVL>
__global__ __launch_bounds__(256) void k_lad(const _Float16* __restrict__ simT,
                                             const float* __restrict__ g0,
                                             float* __restrict__ gout) {
    constexpr float W = (LVL == 0) ? 0.0625f : 0.008f;
    int cid = blockIdx.x >> 2, slice = blockIdx.x & 3;
    int t = threadIdx.x, l = t & 63, wv = t >> 6;
    __shared__ float lo_s;
    if (t == 0) {
        float lo = -1.03125f;
        if (LVL == 1) lo = tau_eval(g0, cid, -1.03125f, 0.0625f);
        lo_s = lo;
    }
    __syncthreads();
    float lo = lo_s;
    const half8* z8 = (const half8*)(simT + (size_t)cid * N_NODES);
    int cnt[32];
    #pragma unroll
    for (int j = 0; j < 32; j++) cnt[j] = 0;
    int base0 = slice * 3125, end = base0 + 3125;   // 12500 half8 chunks total
    for (int base = base0; base < end; base += 256) {
        int i = base + t;
        float b[8];
        #pragma unroll
        for (int j = 0; j < 8; j++) b[j] = -3.f;     // below every threshold
        if (i < end) {
            half8 a = z8[i];
            #pragma unroll
            for (int j = 0; j < 8; j++) b[j] = (float)a[j] - lo;
        }
        #pragma unroll
        for (int j = 0; j < 32; j++) {
            float T = j * W;
            int c0 = __popcll(__ballot(b[0] > T)) + __popcll(__ballot(b[1] > T))
                   + __popcll(__ballot(b[2] > T)) + __popcll(__ballot(b[3] > T));
            int c1 = __popcll(__ballot(b[4] > T)) + __popcll(__ballot(b[5] > T))
                   + __popcll(__ballot(b[6] > T)) + __popcll(__ballot(b[7] > T));
            cnt[j] += c0 + c1;
        }
    }
    __shared__ int red[4][32];
    if (l == 0) {
        #pragma unroll
        for (int j = 0; j < 32; j++) red[wv][j] = cnt[j];
    }
    __syncthreads();
    if (t < 32) {
        float v = (float)(red[0][t] + red[1][t] + red[2][t] + red[3][t]);
        gout[cid * 128 + slice * 32 + t] = v;
    }
}

// ---------------- gather candidates z > thresh (fp16 simT, level-1 threshold) ----------------
__global__ __launch_bounds__(256) void k_gather(const _Float16* __restrict__ simT,
                                                const float* __restrict__ g0,
                                                const float* __restrict__ g1,
                                                int* __restrict__ ccount,
                                                float2* __restrict__ clist) {
    int cid = blockIdx.x >> 2, slice = blockIdx.x & 3;
    __shared__ float th_s;
    if (threadIdx.x == 0) {
        float t1 = tau_eval(g0, cid, -1.03125f, 0.0625f);
        th_s = tau_eval(g1, cid, t1, 0.008f) - 1e-5f;
    }
    __syncthreads();
    float th = th_s;
    const half8* z8 = (const half8*)(simT + (size_t)cid * N_NODES);
    int t = threadIdx.x;
    int end = slice * 3125 + 3125;
    for (int i = slice * 3125 + t; i < end; i += 256) {
        half8 a = z8[i];
        int nb = i * 8;
        #pragma unroll
        for (int j = 0; j < 8; j++) {
            float v = (float)a[j];
            if (v > th) {
                int p = atomicAdd(&ccount[cid], 1);
                if (p < CAP) clist[(size_t)cid * CAP + p] = make_float2(v, __int_as_float(nb + j));
            }
        }
    }
}

// ---------------- exact Michelot on candidates + c_mem accumulation ----------------
__global__ __launch_bounds__(256) void k_csolve(
        const _Float16* __restrict__ simT, const float* __restrict__ new_mem,
        const int* __restrict__ ccount, const float2* __restrict__ clist,
        float* __restrict__ c_mem) {
    int c = blockIdx.x, t = threadIdx.x;  // 256 threads
    __shared__ float zv[CAP];
    __shared__ int   zn[CAP];
    __shared__ float redS[4], redK[4], part[256];
    int raw = ccount[c];
    if (raw == 0) {
        if (t < 128) c_mem[c * 128 + t] = 0.f;
        return;
    }
    float tau;
    if (raw <= CAP) {
        int cnt = raw;
        for (int i = t; i < cnt; i += 256) {
            float2 e = clist[(size_t)c * CAP + i];
            zv[i] = e.x; zn[i] = __float_as_int(e.y);
        }
        __syncthreads();
        float ls = 0.f;
        for (int i = t; i < cnt; i += 256) ls += zv[i];
        #pragma unroll
        for (int m = 1; m < 64; m <<= 1) ls += __shfl_xor(ls, m);
        if ((t & 63) == 0) redS[t >> 6] = ls;
        __syncthreads();
        tau = (redS[0] + redS[1] + redS[2] + redS[3] - 1.f) / (float)cnt;
        float kprev = (float)cnt;
        for (int it = 0; it < 64; it++) {
            float s = 0.f, k = 0.f;
            for (int i = t; i < cnt; i += 256) {
                float v = zv[i];
                if (v > tau) { s += v; k += 1.f; }
            }
            #pragma unroll
            for (int m = 1; m < 64; m <<= 1) { s += __shfl_xor(s, m); k += __shfl_xor(k, m); }
            __syncthreads();
            if ((t & 63) == 0) { redS[t >> 6] = s; redK[t >> 6] = k; }
            __syncthreads();
            float S_ = redS[0] + redS[1] + redS[2] + redS[3];
            float K_ = redK[0] + redK[1] + redK[2] + redK[3];
            if (K_ == kprev || K_ < 0.5f) break;
            kprev = K_;
            tau = (S_ - 1.f) / K_;
        }
        int d = t & 127, half = t >> 7;
        float acc = 0.f;
        for (int i = half; i < cnt; i += 2) {
            float w = zv[i] - tau;
            if (w > 0.f) acc = fmaf(w, new_mem[(size_t)zn[i] * 128 + d], acc);
        }
        part[t] = acc;
        __syncthreads();
        if (t < 128) c_mem[c * 128 + t] = part[t] + part[t + 128];
    } else {
        const _Float16* z = simT + (size_t)c * N_NODES;
        float ls = 0.f;
        for (int n = t; n < N_NODES; n += 256) ls += (float)z[n];
        #pragma unroll
        for (int m = 1; m < 64; m <<= 1) ls += __shfl_xor(ls, m);
        if ((t & 63) == 0) redS[t >> 6] = ls;
        __syncthreads();
        tau = (redS[0] + redS[1] + redS[2] + redS[3] - 1.f) / (float)N_NODES;
        float kprev = -1.f;
        for (int it = 0; it < 64; it++) {
            float s = 0.f, k = 0.f;
            for (int n = t; n < N_NODES; n += 256) {
                float v = (float)z[n];
                if (v > tau) { s += v; k += 1.f; }
            }
            #pragma unroll
            for (int m = 1; m < 64; m <<= 1) { s += __shfl_xor(s, m); k += __shfl_xor(k, m); }
            __syncthreads();
            if ((t & 63) == 0) { redS[t >> 6] = s; redK[t >> 6] = k; }
            __syncthreads();
            float S_ = redS[0] + redS[1] + redS[2] + redS[3];
            float K_ = redK[0] + redK[1] + redK[2] + redK[3];
            if (K_ == kprev || K_ < 0.5f) break;
            kprev = K_;
            tau = (S_ - 1.f) / K_;
        }
        int d = t & 127, half = t >> 7;
        float acc = 0.f;
        for (int n = half; n < N_NODES; n += 2) {
            float w = (float)z[n] - tau;
            if (w > 0.f) acc = fmaf(w, new_mem[(size_t)n * 128 + d], acc);
        }
        part[t] = acc;
        __syncthreads();
        if (t < 128) c_mem[c * 128 + t] = part[t] + part[t + 128];
    }
}

// ---------------- node sparsemax (register Michelot) + ballot-compacted mix -> emb ----------------
__global__ __launch_bounds__(512) void k_emb(
        const _Float16* __restrict__ simT, const float* __restrict__ c_mem,
        float* __restrict__ out) {
    __shared__ float zb[32 * 257];
    __shared__ float2 suppl[32][64];
    __shared__ int suppc[32];
    int t = threadIdx.x;
    int n0 = blockIdx.x * 32;
    // staging: half8 vector loads, 512 threads x 2 iters = 1024 (c,nq) pairs
    #pragma unroll
    for (int r = 0; r < 2; r++) {
        int idx = r * 512 + t;          // 1024 = 256 c x 4 chunks
        int c = idx >> 2, nq = idx & 3;
        half8 v = *(const half8*)&simT[(size_t)c * N_NODES + n0 + nq * 8];
        #pragma unroll
        for (int j = 0; j < 8; j++) zb[(nq * 8 + j) * 257 + c] = (float)v[j];
    }
    __syncthreads();
    int n_l = t >> 4, g = t & 15;
    const float* zr = zb + n_l * 257;
    float zv[16];
    #pragma unroll
    for (int j = 0; j < 16; j++) zv[j] = zr[g + 16 * j];
    float s = 0.f;
    #pragma unroll
    for (int j = 0; j < 16; j++) s += zv[j];
    #pragma unroll
    for (int m = 1; m < 16; m <<= 1) s += __shfl_xor(s, m);
    float tau = (s - 1.f) / 256.f;
    float kprev = -1.f;
    for (int it = 0; it < 40; it++) {
        float ls = 0.f, lk = 0.f;
        #pragma unroll
        for (int j = 0; j < 16; j++) {
            float v = zv[j];
            if (v > tau) { ls += v; lk += 1.f; }
        }
        #pragma unroll
        for (int m = 1; m < 16; m <<= 1) { ls += __shfl_xor(ls, m); lk += __shfl_xor(lk, m); }
        if (lk == kprev) break;
        kprev = lk;
        tau = (ls - 1.f) / lk;
    }
    int gw = (t >> 4) & 3;   // group index within wave
    int base = 0;
    #pragma unroll
    for (int j = 0; j < 16; j++) {
        float m = zv[j] - tau;
        bool pred = m > 0.f;
        unsigned long long mask = __ballot(pred);
        unsigned gm = (unsigned)((mask >> (gw * 16)) & 0xFFFFull);
        if (pred) {
            int idx = base + __popc(gm & ((1u << g) - 1u));
            if (idx < 64) suppl[n_l][idx] = make_float2(m, __int_as_float(g + 16 * j));
        }
        base += __popc(gm);
    }
    if (g == 0) suppc[n_l] = base;
    __syncthreads();
    float acc[8];
    #pragma unroll
    for (int j = 0; j < 8; j++) acc[j] = 0.f;
    int cnt_s = suppc[n_l];
    if (cnt_s <= 64) {
        for (int i = 0; i < cnt_s; i++) {
            float2 e = suppl[n_l][i];
            int c = __float_as_int(e.y);
            const float* cm = c_mem + c * 128 + g * 8;
            #pragma unroll
            for (int j = 0; j < 8; j++) acc[j] = fmaf(e.x, cm[j], acc[j]);
        }
    } else {
        for (int c = 0; c < 256; c++) {
            float m = zr[c] - tau;
            if (m > 0.f) {
                const float* cm = c_mem + c * 128 + g * 8;
                #pragma unroll
                for (int j = 0; j < 8; j++) acc[j] = fmaf(m, cm[j], acc[j]);
            }
        }
    }
    float* op = out + (size_t)(n0 + n_l) * 128 + g * 8;
    #pragma unroll
    for (int j = 0; j < 8; j++) op[j] += acc[j];
}

extern "C" void kernel_launch(void* const* d_in, const int* in_sizes, int n_in,
                              void* d_out, int out_size, void* d_ws, size_t ws_size,
                              hipStream_t stream) {
    const float* node_memory   = (const float*)d_in[0];
    const float* last_update   = (const float*)d_in[1];
    const float* node_features = (const float*)d_in[2];
    const float* event_feat    = (const float*)d_in[3];
    const float* t_arr         = (const float*)d_in[4];
    const int*   src           = (const int*)d_in[5];
    const int*   dst           = (const int*)d_in[6];
    const float* time_w        = (const float*)d_in[7];
    const float* time_b        = (const float*)d_in[8];
    const float* W_ih          = (const float*)d_in[9];
    const float* b_ih          = (const float*)d_in[10];
    const float* W_hh          = (const float*)d_in[11];
    const float* b_hh          = (const float*)d_in[12];
    const float* proj_W        = (const float*)d_in[13];
    const float* proj_b        = (const float*)d_in[14];
    const float* centroids     = (const float*)d_in[15];

    char* wsb      = (char*)d_ws;
    _Float16* simT = (_Float16*)wsb;                          // 256*N halves (51.2 MB)
    int*   cnt_i  = (int*)(wsb + (size_t)256 * N_NODES * 2);  // N ints
    int4*  elist  = (int4*)(cnt_i + N_NODES);                 // N * MAXE int4 (38.4 MB)
    short* Wbf    = (short*)(elist + (size_t)N_NODES * MAXE); // 512*512 bf16
    float* bcat   = (float*)(Wbf + 512 * 512);                // 512
    float* c_mem  = bcat + 512;                               // 256*128 = 32768
    float* gc0    = c_mem + 32768;                            // 256*128
    float* gc1    = gc0 + 32768;
    int*   ccount = (int*)(gc1 + 32768);                      // 256
    float2* clist = (float2*)(ccount + 256);                  // 256*CAP float2
    short* cenf_hi = (short*)(clist + (size_t)256 * CAP);     // 32768 shorts
    short* cenf_lo = cenf_hi + 256 * 128;
    short* pw_hi   = cenf_lo + 256 * 128;
    short* pw_lo   = pw_hi + 128 * 128;
    float* out    = (float*)d_out;

    hipMemsetAsync(cnt_i, 0, N_NODES * sizeof(int), stream);
    hipMemsetAsync(ccount, 0, 256 * sizeof(int), stream);
    k_build<<<1024, 256, 0, stream>>>(W_ih, b_ih, W_hh, b_hh, Wbf, bcat);
    k_cen<<<256, 128, 0, stream>>>(centroids, cenf_hi, cenf_lo);
    k_packW<<<64, 256, 0, stream>>>(proj_W, pw_hi, pw_lo);
    k_fill<<<(2 * N_EV + 255) / 256, 256, 0, stream>>>(t_arr, src, dst, cnt_i, elist);
    k_gru<<<N_NODES / 32, 512, 0, stream>>>(node_memory, last_update, event_feat,
                                            time_w, time_b, cnt_i, elist, Wbf, bcat, out);
    k_sim<<<(N_NODES + 63) / 64, 256, 0, stream>>>(out, node_features, pw_hi, pw_lo,
                                                   proj_b, cenf_hi, cenf_lo, simT);
    k_lad<0><<<1024, 256, 0, stream>>>(simT, nullptr, gc0);
    k_lad<1><<<1024, 256, 0, stream>>>(simT, gc0, gc1);
    k_gather<<<1024, 256, 0, stream>>>(simT, gc0, gc1, ccount, clist);
    k_csolve<<<256, 256, 0, stream>>>(simT, out, ccount, clist, c_mem);
    k_emb<<<N_NODES / 32, 512, 0, stream>>>(simT, c_mem, out);
}